// Round 1
// baseline (724.872 us; speedup 1.0000x reference)
//
#include <hip/hip_runtime.h>
#include <hip/hip_bf16.h>

#define E_ 128
#define NSAMP 2048

typedef __attribute__((ext_vector_type(8))) short short8;
typedef __attribute__((ext_vector_type(4))) float floatx4;

__device__ __forceinline__ ushort f2b(float f) {
    union { __hip_bfloat16 h; ushort u; } cv;
    cv.h = __float2bfloat16(f);
    return cv.u;
}

__device__ __forceinline__ void gload_lds16(const ushort* g, ushort* l) {
    __builtin_amdgcn_global_load_lds(
        (const __attribute__((address_space(1))) void*)g,
        (__attribute__((address_space(3))) void*)l, 16, 0, 0);
}

// -------------------- h = ReLU(ids @ l1W^T + l1b), fp32 --------------------
__global__ void hyper_h(const float* __restrict__ input, const float* __restrict__ l1W,
                        const float* __restrict__ l1b, float* __restrict__ h)
{
    int b = blockIdx.x / 5;
    int o = (blockIdx.x % 5) * 256 + threadIdx.x;
    const float* ids = input + (size_t)b * 192 + 176;
    const float* w = l1W + (size_t)o * 16;
    float a = l1b[o];
#pragma unroll
    for (int i = 0; i < 16; i += 4) {
        float4 wv = *(const float4*)(w + i);
        a += ids[i] * wv.x + ids[i + 1] * wv.y + ids[i + 2] * wv.z + ids[i + 3] * wv.w;
    }
    h[(size_t)b * 1280 + o] = fmaxf(a, 0.f);
}

// -------------------- xT0[s][b] = input[b][s]  (s < 176), fp32 --------------------
__global__ void x0_t(const float* __restrict__ input, float* __restrict__ xT0)
{
    int idx = blockIdx.x * 256 + threadIdx.x;   // < 176*2048
    int s = idx >> 11, b = idx & 2047;
    xT0[idx] = input[(size_t)b * 192 + s];
}

// -------------------- fp32 -> bf16 convert (wW bulk) --------------------
__global__ void cvt_bf16(const float* __restrict__ src, ushort* __restrict__ dst, int n)
{
    int i = (blockIdx.x * 256 + threadIdx.x) * 8;
    if (i >= n) return;
    float4 a = *(const float4*)(src + i);
    float4 b = *(const float4*)(src + i + 4);
    union { ushort o[8]; uint4 v; } u;
    u.o[0] = f2b(a.x); u.o[1] = f2b(a.y); u.o[2] = f2b(a.z); u.o[3] = f2b(a.w);
    u.o[4] = f2b(b.x); u.o[5] = f2b(b.y); u.o[6] = f2b(b.z); u.o[7] = f2b(b.w);
    *(uint4*)(dst + i) = u.v;
}

// -------------------- build 3 virtual B-slices: [S]=bW rows, [S+1..S+2]=wb^T chunks --------
__global__ void cvt_bias(const float* __restrict__ bW, const float* __restrict__ wb,
                         ushort* __restrict__ dst, int S, int M)
{
    int idx = blockIdx.x * 256 + threadIdx.x;   // < 3*M*E_
    int slice = idx / (M * E_);
    int rem = idx - slice * (M * E_);
    int m = rem / E_, e = rem - m * E_;
    ushort v;
    if (slice == 0) {
        v = f2b(bW[(size_t)m * E_ + e]);
    } else {
        int s = (slice - 1) * 128 + e;
        v = (s < S) ? f2b(wb[(size_t)s * M + m]) : (ushort)0;
    }
    dst[(size_t)(S + slice) * M * E_ + rem] = v;
}

// ==================== big-layer GEMM (M=256): pipelined async LDS staging ====================
// BM=BN=128, 4 waves (2x2), BK=64 per phase.
// Pipelined main loop (s < S only): Bs double-buffered, DMA issued 2 phases ahead,
// counted s_waitcnt vmcnt(4) + raw s_barrier (never drains to 0 mid-loop).
// As single buffer, generated 1 phase ahead by VALU from LDS-staged x-slice (xs) + hreg.
// XOR-swizzled 16B groups as before: group g of row r stored at g ^ (r&7).
// Virtual slices (s >= S) peeled into a slow non-pipelined epilogue (1 of ksplit blocks).
__global__ __launch_bounds__(256, 2) void gemm_big(
    const ushort* __restrict__ wWb, const float* __restrict__ h,
    const float* __restrict__ xT, float* __restrict__ partial,
    int S, int iw, int ksplit, int btiles, int ntiles)
{
    __shared__ __align__(16) ushort As[128 * 64];
    __shared__ __align__(16) ushort Bs[2][128 * 64];
    __shared__ __align__(16) float xs[17 * 128];

    const int tid = threadIdx.x;
    const int bt = blockIdx.x % btiles;
    const int nt = (blockIdx.x / btiles) % ntiles;
    const int ks = blockIdx.x / (btiles * ntiles);
    const int b0 = bt * 128;
    const int m0 = nt * 128;
    const int total_s = S + 3;
    const int base = total_s / ksplit;
    const int rem = total_s - base * ksplit;
    const int s0 = ks * base + min(ks, rem);
    const int s1v = s0 + base + (ks < rem ? 1 : 0);
    const int sE = min(s1v, S);     // main-loop covers [s0, sE); virtual slices peeled
    const int ns = sE - s0;         // >= 1 for all blocks at these shapes
    const int T = 2 * ns;           // phase count

    const int lane = tid & 63;
    const int wave = tid >> 6;
    const int quad = lane >> 4;
    const int lr = lane & 15;
    const int wm0 = (wave >> 1) * 64;
    const int wn0 = (wave & 1) * 64;

    const int tb = tid >> 3;            // A-gen row (0..31), +32*k2
    const int teg = tid & 7;            // A-gen e-group
    const int aswz = (teg ^ (tb & 7)) * 8;   // swizzled A slot (shorts)

    const int brow = lane >> 3;         // B-DMA local row (0..7)
    const int bgg = (lane & 7) ^ brow;  // global e-group for this lane's slot

    // preload h chunk (iw) fp32: hreg[k2][p][j] = h[b0+tb+32k2][iw*128 + p*64 + teg*8 + j]
    float hreg[4][2][8];
#pragma unroll
    for (int k2 = 0; k2 < 4; ++k2) {
#pragma unroll
        for (int p = 0; p < 2; ++p) {
            const float* src = h + (size_t)(b0 + tb + 32 * k2) * 1280 + (size_t)iw * E_ + p * 64 + teg * 8;
            float4 v0 = *(const float4*)(src);
            float4 v1 = *(const float4*)(src + 4);
            hreg[k2][p][0] = v0.x; hreg[k2][p][1] = v0.y; hreg[k2][p][2] = v0.z; hreg[k2][p][3] = v0.w;
            hreg[k2][p][4] = v1.x; hreg[k2][p][5] = v1.y; hreg[k2][p][6] = v1.z; hreg[k2][p][7] = v1.w;
        }
    }

    // stage this block's x-slice into LDS (keeps steady-state loop free of global loads)
    for (int idx = tid; idx < ns * 128; idx += 256) {
        int j = idx >> 7, bb2 = idx & 127;
        xs[idx] = xT[(size_t)(s0 + j) * NSAMP + b0 + bb2];
    }

    floatx4 acc[4][4];
#pragma unroll
    for (int i = 0; i < 4; ++i)
#pragma unroll
        for (int j = 0; j < 4; ++j)
            acc[i][j] = (floatx4){0.f, 0.f, 0.f, 0.f};

    auto dmaB = [&](int s, int p, ushort* buf) {
#pragma unroll
        for (int t4 = 0; t4 < 4; ++t4) {
            int rloc = wave * 32 + t4 * 8;
            const ushort* gp = wWb + ((size_t)s * 256 + m0 + rloc + brow) * E_ + p * 64 + bgg * 8;
            gload_lds16(gp, buf + (size_t)rloc * 64 + lane * 8);
        }
    };
    auto genA = [&](int s, int p) {
        float xv[4];
#pragma unroll
        for (int k2 = 0; k2 < 4; ++k2) xv[k2] = xs[(s - s0) * 128 + tb + 32 * k2];
#pragma unroll
        for (int k2 = 0; k2 < 4; ++k2) {
            union { ushort o[8]; uint4 v; } u;
#pragma unroll
            for (int j = 0; j < 8; ++j) u.o[j] = f2b(xv[k2] * hreg[k2][p][j]);
            *(uint4*)&As[(size_t)(tb + 32 * k2) * 64 + aswz] = u.v;
        }
    };

    // prologue: A(0) staged; full drain (also resolves hreg/xs loads in the compiler's
    // scoreboard so no waits land inside the loop); then B(0),B(1) DMA in flight.
    genA(s0, 0);
    __syncthreads();
    __builtin_amdgcn_sched_barrier(0);
    dmaB(s0, 0, Bs[0]);
    dmaB(s0, 1, Bs[1]);

    for (int t = 0; t < T; ++t) {
        const int cur = t & 1;
        // need B(t) landed; B(t+1) (4 loads) stays in flight except at the last phase
        if (t + 1 < T) {
            asm volatile("s_waitcnt vmcnt(4) lgkmcnt(0)" ::: "memory");
        } else {
            asm volatile("s_waitcnt vmcnt(0) lgkmcnt(0)" ::: "memory");
        }
        __builtin_amdgcn_sched_barrier(0);
        __builtin_amdgcn_s_barrier();          // buffers for phase t fully staged
        __builtin_amdgcn_sched_barrier(0);

        // fragment reads (must complete before barrier2: staging overwrites As/Bs[cur])
        short8 af[2][4], bfr[2][4];
#pragma unroll
        for (int kk = 0; kk < 2; ++kk) {
            const int swz = ((kk * 4 + quad) ^ (lr & 7)) * 8;
#pragma unroll
            for (int i = 0; i < 4; ++i)
                af[kk][i] = *(const short8*)&As[(size_t)(wm0 + i * 16 + lr) * 64 + swz];
#pragma unroll
            for (int j = 0; j < 4; ++j)
                bfr[kk][j] = *(const short8*)&Bs[cur][(size_t)(wn0 + j * 16 + lr) * 64 + swz];
        }
        asm volatile("s_waitcnt lgkmcnt(0)" ::: "memory");
        __builtin_amdgcn_sched_barrier(0);
        __builtin_amdgcn_s_barrier();          // all waves done reading
        __builtin_amdgcn_sched_barrier(0);

        // stage ahead: B(t+2) DMA (flies across next phase), A(t+1) via VALU
        if (t + 2 < T) dmaB(s0 + ((t + 2) >> 1), (t + 2) & 1, Bs[cur]);
        if (t + 1 < T) genA(s0 + ((t + 1) >> 1), (t + 1) & 1);

        __builtin_amdgcn_s_setprio(1);
#pragma unroll
        for (int kk = 0; kk < 2; ++kk)
#pragma unroll
            for (int i = 0; i < 4; ++i)
#pragma unroll
                for (int j = 0; j < 4; ++j)
                    acc[i][j] = __builtin_amdgcn_mfma_f32_16x16x32_bf16(af[kk][i], bfr[kk][j], acc[i][j], 0, 0, 0);
        __builtin_amdgcn_s_setprio(0);
    }

    // ---- epilogue: virtual slices s in [S, s1v), non-pipelined (rare: 1 of ksplit blocks) ----
    for (int s = sE; s < s1v; ++s) {
#pragma unroll
        for (int p = 0; p < 2; ++p) {
            __syncthreads();   // full drain; previous phase's reads complete
            dmaB(s, p, Bs[0]);
            if (s == S) {
#pragma unroll
                for (int k2 = 0; k2 < 4; ++k2) {
                    const float* src = h + (size_t)(b0 + tb + 32 * k2) * 1280
                                         + (size_t)(iw + 1) * E_ + p * 64 + teg * 8;
                    float4 v0 = *(const float4*)(src);
                    float4 v1 = *(const float4*)(src + 4);
                    union { ushort o[8]; uint4 v; } u;
                    u.o[0] = f2b(v0.x); u.o[1] = f2b(v0.y); u.o[2] = f2b(v0.z); u.o[3] = f2b(v0.w);
                    u.o[4] = f2b(v1.x); u.o[5] = f2b(v1.y); u.o[6] = f2b(v1.z); u.o[7] = f2b(v1.w);
                    *(uint4*)&As[(size_t)(tb + 32 * k2) * 64 + aswz] = u.v;
                }
            } else {
                int j0 = (s - S - 1) * 128 + p * 64 + teg * 8;
#pragma unroll
                for (int k2 = 0; k2 < 4; ++k2) {
                    int b = b0 + tb + 32 * k2;
                    union { ushort o[8]; uint4 v; } u;
#pragma unroll
                    for (int jj = 0; jj < 8; ++jj) {
                        int sp = j0 + jj;
                        u.o[jj] = (sp < S) ? f2b(xT[(size_t)sp * NSAMP + b]) : (ushort)0;
                    }
                    *(uint4*)&As[(size_t)(tb + 32 * k2) * 64 + aswz] = u.v;
                }
            }
            __syncthreads();   // staging (incl. DMA via vmcnt drain) visible
#pragma unroll
            for (int kk = 0; kk < 2; ++kk) {
                const int swz = ((kk * 4 + quad) ^ (lr & 7)) * 8;
                short8 af2[4], bf2[4];
#pragma unroll
                for (int i = 0; i < 4; ++i)
                    af2[i] = *(const short8*)&As[(size_t)(wm0 + i * 16 + lr) * 64 + swz];
#pragma unroll
                for (int j = 0; j < 4; ++j)
                    bf2[j] = *(const short8*)&Bs[0][(size_t)(wn0 + j * 16 + lr) * 64 + swz];
#pragma unroll
                for (int i = 0; i < 4; ++i)
#pragma unroll
                    for (int j = 0; j < 4; ++j)
                        acc[i][j] = __builtin_amdgcn_mfma_f32_16x16x32_bf16(af2[i], bf2[j], acc[i][j], 0, 0, 0);
            }
        }
    }

    // epilogue: C/D layout col=lane&15, row=quad*4+r
    float* dst = partial + (size_t)ks * NSAMP * 256;
#pragma unroll
    for (int i = 0; i < 4; ++i)
#pragma unroll
        for (int j = 0; j < 4; ++j)
#pragma unroll
            for (int r = 0; r < 4; ++r) {
                int row = wm0 + i * 16 + quad * 4 + r;
                int col = wn0 + j * 16 + lr;
                dst[(size_t)(b0 + row) * 256 + m0 + col] = acc[i][j][r];
            }
}

// ==================== small-layer GEMM (M=16) — previous structure ====================
template<int BM, int BN, int WROWS, int WCOLS>
__global__ __launch_bounds__(256, 2) void gemm_k(
    const ushort* __restrict__ wWb, const float* __restrict__ h,
    const float* __restrict__ xT, float* __restrict__ partial,
    int S, int M, int iw, int ksplit, int btiles, int ntiles)
{
    constexpr int SM = BM / WROWS / 16;
    constexpr int SN = BN / WCOLS / 16;
    constexpr int ASLOTS = BM * 8 / 256;
    constexpr int LDA = 72;

    __shared__ ushort As[BM][LDA];
    __shared__ ushort Bs[BN][LDA];

    const int tid = threadIdx.x;
    const int bt = blockIdx.x % btiles;
    const int nt = (blockIdx.x / btiles) % ntiles;
    const int ks = blockIdx.x / (btiles * ntiles);
    const int b0 = bt * BM;
    const int m0 = nt * BN;
    const int total_s = S + 3;
    const int base = total_s / ksplit;
    const int rem = total_s - base * ksplit;
    const int s0 = ks * base + min(ks, rem);
    const int s1 = s0 + base + (ks < rem ? 1 : 0);

    const int lane = tid & 63;
    const int wave = tid >> 6;
    const int quad = lane >> 4;
    const int lr = lane & 15;
    const int wm0 = (wave / WCOLS) * (BM / WROWS);
    const int wn0 = (wave % WCOLS) * (BN / WCOLS);

    const int tb = tid >> 3;
    const int teg = tid & 7;

    float hreg[ASLOTS][2][8];
#pragma unroll
    for (int k2 = 0; k2 < ASLOTS; ++k2) {
        int b = tb + 32 * k2;
#pragma unroll
        for (int p = 0; p < 2; ++p) {
            const float* src = h + (size_t)(b0 + b) * 1280 + (size_t)iw * E_ + p * 64 + teg * 8;
            float4 v0 = *(const float4*)(src);
            float4 v1 = *(const float4*)(src + 4);
            hreg[k2][p][0] = v0.x; hreg[k2][p][1] = v0.y; hreg[k2][p][2] = v0.z; hreg[k2][p][3] = v0.w;
            hreg[k2][p][4] = v1.x; hreg[k2][p][5] = v1.y; hreg[k2][p][6] = v1.z; hreg[k2][p][7] = v1.w;
        }
    }

    floatx4 acc[SM][SN];
#pragma unroll
    for (int i = 0; i < SM; ++i)
#pragma unroll
        for (int j = 0; j < SN; ++j)
            acc[i][j] = (floatx4){0.f, 0.f, 0.f, 0.f};

    for (int s = s0; s < s1; ++s) {
        float xv[ASLOTS];
        if (s < S) {
#pragma unroll
            for (int k2 = 0; k2 < ASLOTS; ++k2)
                xv[k2] = xT[(size_t)s * NSAMP + b0 + tb + 32 * k2];
        }

#pragma unroll
        for (int p = 0; p < 2; ++p) {
            if (s < S) {
#pragma unroll
                for (int k2 = 0; k2 < ASLOTS; ++k2) {
                    union { ushort o[8]; uint4 v; } u;
#pragma unroll
                    for (int j = 0; j < 8; ++j) u.o[j] = f2b(xv[k2] * hreg[k2][p][j]);
                    *(uint4*)&As[tb + 32 * k2][teg * 8] = u.v;
                }
            } else if (s == S) {
#pragma unroll
                for (int k2 = 0; k2 < ASLOTS; ++k2) {
                    const float* src = h + (size_t)(b0 + tb + 32 * k2) * 1280
                                         + (size_t)(iw + 1) * E_ + p * 64 + teg * 8;
                    float4 v0 = *(const float4*)(src);
                    float4 v1 = *(const float4*)(src + 4);
                    union { ushort o[8]; uint4 v; } u;
                    u.o[0] = f2b(v0.x); u.o[1] = f2b(v0.y); u.o[2] = f2b(v0.z); u.o[3] = f2b(v0.w);
                    u.o[4] = f2b(v1.x); u.o[5] = f2b(v1.y); u.o[6] = f2b(v1.z); u.o[7] = f2b(v1.w);
                    *(uint4*)&As[tb + 32 * k2][teg * 8] = u.v;
                }
            } else {
                int j0 = (s - S - 1) * 128 + p * 64 + teg * 8;
#pragma unroll
                for (int k2 = 0; k2 < ASLOTS; ++k2) {
                    int b = b0 + tb + 32 * k2;
                    union { ushort o[8]; uint4 v; } u;
#pragma unroll
                    for (int jj = 0; jj < 8; ++jj) {
                        int sp = j0 + jj;
                        u.o[jj] = (sp < S) ? f2b(xT[(size_t)sp * NSAMP + b]) : (ushort)0;
                    }
                    *(uint4*)&As[tb + 32 * k2][teg * 8] = u.v;
                }
            }
#pragma unroll
            for (int slot = tid; slot < BN * 8; slot += 256) {
                int m = slot >> 3, eg2 = slot & 7;
                *(uint4*)&Bs[m][eg2 * 8] =
                    *(const uint4*)(wWb + ((size_t)s * M + m0 + m) * E_ + p * 64 + eg2 * 8);
            }
            __syncthreads();
#pragma unroll
            for (int kk = 0; kk < 2; ++kk) {
                short8 af[SM], bfr[SN];
#pragma unroll
                for (int i = 0; i < SM; ++i)
                    af[i] = *(const short8*)&As[wm0 + i * 16 + lr][kk * 32 + quad * 8];
#pragma unroll
                for (int j = 0; j < SN; ++j)
                    bfr[j] = *(const short8*)&Bs[wn0 + j * 16 + lr][kk * 32 + quad * 8];
#pragma unroll
                for (int i = 0; i < SM; ++i)
#pragma unroll
                    for (int j = 0; j < SN; ++j)
                        acc[i][j] = __builtin_amdgcn_mfma_f32_16x16x32_bf16(af[i], bfr[j], acc[i][j], 0, 0, 0);
            }
            __syncthreads();
        }
    }

    float* dst = partial + (size_t)ks * NSAMP * M;
#pragma unroll
    for (int i = 0; i < SM; ++i)
#pragma unroll
        for (int j = 0; j < SN; ++j)
#pragma unroll
            for (int r = 0; r < 4; ++r) {
                int row = wm0 + i * 16 + quad * 4 + r;
                int col = wn0 + j * 16 + lr;
                dst[(size_t)(b0 + row) * M + m0 + col] = acc[i][j][r];
            }
}

// -------------------- reduce partials + bb (+ReLU), emit xT fp32 for next layer --------------
__global__ void reduce_mid(const float* __restrict__ partial, const float* __restrict__ bb,
                           float* __restrict__ xTn, int KS, int relu)
{
    __shared__ float t[32][33];
    const int b0 = (blockIdx.x >> 3) * 32;
    const int m0 = (blockIdx.x & 7) * 32;
    const int mo = threadIdx.x & 31;
    const int bs0 = threadIdx.x >> 5;   // 0..7
    const float bv = bb[m0 + mo];
#pragma unroll
    for (int r = 0; r < 4; ++r) {
        const int bs = bs0 + 8 * r;
        const size_t off = (size_t)(b0 + bs) * 256 + m0 + mo;
        float a0 = 0.f, a1 = 0.f, a2 = 0.f, a3 = 0.f;
#pragma unroll
        for (int k = 0; k < 16; k += 4) {
            a0 += partial[(size_t)(k + 0) * (NSAMP * 256) + off];
            a1 += partial[(size_t)(k + 1) * (NSAMP * 256) + off];
            a2 += partial[(size_t)(k + 2) * (NSAMP * 256) + off];
            a3 += partial[(size_t)(k + 3) * (NSAMP * 256) + off];
        }
        float a = (a0 + a1) + (a2 + a3) + bv;
        if (relu) a = fmaxf(a, 0.f);
        t[bs][mo] = a;
    }
    __syncthreads();
    const int bo = threadIdx.x & 31;
    const int ms0 = threadIdx.x >> 5;
#pragma unroll
    for (int r = 0; r < 4; ++r) {
        const int ms = ms0 + 8 * r;
        xTn[(size_t)(m0 + ms) * NSAMP + b0 + bo] = t[bo][ms];
    }
}

// -------------------- final layer reduce -> d_out (fp32, ReLU) --------------------
__global__ void reduce_out(const float* __restrict__ partial, const float* __restrict__ bb,
                           float* __restrict__ out, int KS)
{
    int idx = blockIdx.x * 256 + threadIdx.x;   // < 2048*16
    float a0 = 0.f, a1 = 0.f, a2 = 0.f, a3 = 0.f;
#pragma unroll
    for (int k = 0; k < 64; k += 4) {
        a0 += partial[(size_t)(k + 0) * (NSAMP * 16) + idx];
        a1 += partial[(size_t)(k + 1) * (NSAMP * 16) + idx];
        a2 += partial[(size_t)(k + 2) * (NSAMP * 16) + idx];
        a3 += partial[(size_t)(k + 3) * (NSAMP * 16) + idx];
    }
    out[idx] = fmaxf((a0 + a1) + (a2 + a3) + bb[idx & 15], 0.f);
}

extern "C" void kernel_launch(void* const* d_in, const int* in_sizes, int n_in,
                              void* d_out, int out_size, void* d_ws, size_t ws_size,
                              hipStream_t stream)
{
    const float* input = (const float*)d_in[0];
    const float* l1W   = (const float*)d_in[1];
    const float* l1b   = (const float*)d_in[2];

    char* ws = (char*)d_ws;
    // layout (bytes): wWb 16.98M | h 10.49M | xT0 2M | xT1 2M | partial 33.55M = 65.2MB
    ushort* wWb = (ushort*)(ws + 0);
    float* h    = (float*)(ws + 16975872);
    float* xT0  = (float*)(ws + 27461632);
    float* xT1  = (float*)(ws + 29558784);
    float* part = (float*)(ws + 31655936);

    hipLaunchKernelGGL(hyper_h, dim3(2048 * 5), dim3(256), 0, stream, input, l1W, l1b, h);
    hipLaunchKernelGGL(x0_t, dim3(176 * 2048 / 256), dim3(256), 0, stream, input, xT0);

    const int S_[5] = {176, 256, 256, 256, 256};
    const int M_[5] = {256, 256, 256, 256, 16};
    float* xt[2] = {xT0, xT1};

    for (int i = 0; i < 5; ++i) {
        const float* wW = (const float*)d_in[3 + 4 * i];
        const float* wb = (const float*)d_in[4 + 4 * i];
        const float* bW = (const float*)d_in[5 + 4 * i];
        const float* bb = (const float*)d_in[6 + 4 * i];
        float* xin = xt[i & 1];
        int n = S_[i] * M_[i] * E_;
        hipLaunchKernelGGL(cvt_bf16, dim3(n / 2048), dim3(256), 0, stream, wW, wWb, n);
        hipLaunchKernelGGL(cvt_bias, dim3(3 * M_[i] * E_ / 256), dim3(256), 0, stream,
                           bW, wb, wWb, S_[i], M_[i]);

        if (M_[i] == 256) {
            const int btiles = 16, ntiles = 2, ksplit = 16;
            hipLaunchKernelGGL(gemm_big, dim3(btiles * ntiles * ksplit), dim3(256), 0, stream,
                               wWb, h, xin, part, S_[i], 2 * i, ksplit, btiles, ntiles);
            hipLaunchKernelGGL(reduce_mid, dim3(512), dim3(256), 0, stream,
                               part, bb, xt[(i + 1) & 1], ksplit, (i < 3) ? 1 : 0);
        } else {
            const int btiles = 8, ntiles = 1, ksplit = 64;
            hipLaunchKernelGGL((gemm_k<256, 16, 4, 1>), dim3(btiles * ntiles * ksplit), dim3(256), 0, stream,
                               wWb, h, xin, part, S_[i], 16, 2 * i, ksplit, btiles, ntiles);
            hipLaunchKernelGGL(reduce_out, dim3(128), dim3(256), 0, stream,
                               part, bb, (float*)d_out, ksplit);
        }
    }
}

// Round 2
// 713.259 us; speedup vs baseline: 1.0163x; 1.0163x over previous
//
#include <hip/hip_runtime.h>
#include <hip/hip_bf16.h>

#define E_ 128
#define NSAMP 2048

typedef __attribute__((ext_vector_type(8))) short short8;
typedef __attribute__((ext_vector_type(4))) float floatx4;

__device__ __forceinline__ ushort f2b(float f) {
    union { __hip_bfloat16 h; ushort u; } cv;
    cv.h = __float2bfloat16(f);
    return cv.u;
}

__device__ __forceinline__ void gload_lds16(const ushort* g, ushort* l) {
    __builtin_amdgcn_global_load_lds(
        (const __attribute__((address_space(1))) void*)g,
        (__attribute__((address_space(3))) void*)l, 16, 0, 0);
}

// -------------------- h = ReLU(ids @ l1W^T + l1b), fp32 --------------------
__global__ void hyper_h(const float* __restrict__ input, const float* __restrict__ l1W,
                        const float* __restrict__ l1b, float* __restrict__ h)
{
    int b = blockIdx.x / 5;
    int o = (blockIdx.x % 5) * 256 + threadIdx.x;
    const float* ids = input + (size_t)b * 192 + 176;
    const float* w = l1W + (size_t)o * 16;
    float a = l1b[o];
#pragma unroll
    for (int i = 0; i < 16; i += 4) {
        float4 wv = *(const float4*)(w + i);
        a += ids[i] * wv.x + ids[i + 1] * wv.y + ids[i + 2] * wv.z + ids[i + 3] * wv.w;
    }
    h[(size_t)b * 1280 + o] = fmaxf(a, 0.f);
}

// -------------------- xT0[s][b] = input[b][s]  (s < 176), fp32 --------------------
__global__ void x0_t(const float* __restrict__ input, float* __restrict__ xT0)
{
    int idx = blockIdx.x * 256 + threadIdx.x;   // < 176*2048
    int s = idx >> 11, b = idx & 2047;
    xT0[idx] = input[(size_t)b * 192 + s];
}

// -------------------- fp32 -> bf16 convert (wW bulk) --------------------
__global__ void cvt_bf16(const float* __restrict__ src, ushort* __restrict__ dst, int n)
{
    int i = (blockIdx.x * 256 + threadIdx.x) * 8;
    if (i >= n) return;
    float4 a = *(const float4*)(src + i);
    float4 b = *(const float4*)(src + i + 4);
    union { ushort o[8]; uint4 v; } u;
    u.o[0] = f2b(a.x); u.o[1] = f2b(a.y); u.o[2] = f2b(a.z); u.o[3] = f2b(a.w);
    u.o[4] = f2b(b.x); u.o[5] = f2b(b.y); u.o[6] = f2b(b.z); u.o[7] = f2b(b.w);
    *(uint4*)(dst + i) = u.v;
}

// -------------------- build 3 virtual B-slices: [S]=bW rows, [S+1..S+2]=wb^T chunks --------
__global__ void cvt_bias(const float* __restrict__ bW, const float* __restrict__ wb,
                         ushort* __restrict__ dst, int S, int M)
{
    int idx = blockIdx.x * 256 + threadIdx.x;   // < 3*M*E_
    int slice = idx / (M * E_);
    int rem = idx - slice * (M * E_);
    int m = rem / E_, e = rem - m * E_;
    ushort v;
    if (slice == 0) {
        v = f2b(bW[(size_t)m * E_ + e]);
    } else {
        int s = (slice - 1) * 128 + e;
        v = (s < S) ? f2b(wb[(size_t)s * M + m]) : (ushort)0;
    }
    dst[(size_t)(S + slice) * M * E_ + rem] = v;
}

// ==================== big-layer GEMM (M=256): pipelined + XCD-colocated combos ====================
// BM=BN=128, 4 waves (2x2), BK=64 per phase.
// Pipelined main loop (s < S only): Bs double-buffered, DMA issued 2 phases ahead,
// counted s_waitcnt vmcnt(4) + raw s_barrier (never drains to 0 mid-loop).
// As single buffer, generated 1 phase ahead by VALU from LDS-staged x-slice (xs) + hreg.
// Block swizzle: combo (nt,ks) pinned to one XCD, its 16 bt-blocks contiguous there ->
// 4 combos/XCD = 2.1MB wWb working set fits the 4MB per-XCD L2 (restores 16x reuse that
// round-1's drift destroyed: FETCH 69->254MB).
__global__ __launch_bounds__(256, 2) void gemm_big(
    const ushort* __restrict__ wWb, const float* __restrict__ h,
    const float* __restrict__ xT, float* __restrict__ partial,
    int S, int iw, int ksplit, int btiles, int ntiles)
{
    __shared__ __align__(16) ushort As[128 * 64];
    __shared__ __align__(16) ushort Bs[2][128 * 64];
    __shared__ __align__(16) float xs[17 * 128];

    const int tid = threadIdx.x;
    // ---- XCD-aware decode: xcd = bid%8 (HW round-robin), 16 consecutive same-XCD slots
    // get the same combo; combo c lands on XCD c%8. Bijective for grid = 8*btiles*n.
    const int bid = blockIdx.x;
    const int xcd = bid & 7;
    const int jj_ = bid >> 3;
    const int combo = xcd + 8 * (jj_ / btiles);
    const int bt = jj_ % btiles;
    const int nt = combo % ntiles;
    const int ks = combo / ntiles;
    const int b0 = bt * 128;
    const int m0 = nt * 128;
    const int total_s = S + 3;
    const int base = total_s / ksplit;
    const int rem = total_s - base * ksplit;
    const int s0 = ks * base + min(ks, rem);
    const int s1v = s0 + base + (ks < rem ? 1 : 0);
    const int sE = min(s1v, S);     // main-loop covers [s0, sE); virtual slices peeled
    const int ns = sE - s0;         // >= 1 for all blocks at these shapes
    const int T = 2 * ns;           // phase count

    const int lane = tid & 63;
    const int wave = tid >> 6;
    const int quad = lane >> 4;
    const int lr = lane & 15;
    const int wm0 = (wave >> 1) * 64;
    const int wn0 = (wave & 1) * 64;

    const int tb = tid >> 3;            // A-gen row (0..31), +32*k2
    const int teg = tid & 7;            // A-gen e-group
    const int aswz = (teg ^ (tb & 7)) * 8;   // swizzled A slot (shorts)

    const int brow = lane >> 3;         // B-DMA local row (0..7)
    const int bgg = (lane & 7) ^ brow;  // global e-group for this lane's slot

    // preload h chunk (iw) fp32: hreg[k2][p][j] = h[b0+tb+32k2][iw*128 + p*64 + teg*8 + j]
    float hreg[4][2][8];
#pragma unroll
    for (int k2 = 0; k2 < 4; ++k2) {
#pragma unroll
        for (int p = 0; p < 2; ++p) {
            const float* src = h + (size_t)(b0 + tb + 32 * k2) * 1280 + (size_t)iw * E_ + p * 64 + teg * 8;
            float4 v0 = *(const float4*)(src);
            float4 v1 = *(const float4*)(src + 4);
            hreg[k2][p][0] = v0.x; hreg[k2][p][1] = v0.y; hreg[k2][p][2] = v0.z; hreg[k2][p][3] = v0.w;
            hreg[k2][p][4] = v1.x; hreg[k2][p][5] = v1.y; hreg[k2][p][6] = v1.z; hreg[k2][p][7] = v1.w;
        }
    }

    // stage this block's x-slice into LDS (keeps steady-state loop free of global loads)
    for (int idx = tid; idx < ns * 128; idx += 256) {
        int j = idx >> 7, bb2 = idx & 127;
        xs[idx] = xT[(size_t)(s0 + j) * NSAMP + b0 + bb2];
    }

    floatx4 acc[4][4];
#pragma unroll
    for (int i = 0; i < 4; ++i)
#pragma unroll
        for (int j = 0; j < 4; ++j)
            acc[i][j] = (floatx4){0.f, 0.f, 0.f, 0.f};

    auto dmaB = [&](int s, int p, ushort* buf) {
#pragma unroll
        for (int t4 = 0; t4 < 4; ++t4) {
            int rloc = wave * 32 + t4 * 8;
            const ushort* gp = wWb + ((size_t)s * 256 + m0 + rloc + brow) * E_ + p * 64 + bgg * 8;
            gload_lds16(gp, buf + (size_t)rloc * 64 + lane * 8);
        }
    };
    auto genA = [&](int s, int p) {
        float xv[4];
#pragma unroll
        for (int k2 = 0; k2 < 4; ++k2) xv[k2] = xs[(s - s0) * 128 + tb + 32 * k2];
#pragma unroll
        for (int k2 = 0; k2 < 4; ++k2) {
            union { ushort o[8]; uint4 v; } u;
#pragma unroll
            for (int j = 0; j < 8; ++j) u.o[j] = f2b(xv[k2] * hreg[k2][p][j]);
            *(uint4*)&As[(size_t)(tb + 32 * k2) * 64 + aswz] = u.v;
        }
    };

    // prologue: A(0) staged; full drain (also resolves hreg/xs loads in the compiler's
    // scoreboard so no waits land inside the loop); then B(0),B(1) DMA in flight.
    genA(s0, 0);
    __syncthreads();
    __builtin_amdgcn_sched_barrier(0);
    dmaB(s0, 0, Bs[0]);
    dmaB(s0, 1, Bs[1]);

    for (int t = 0; t < T; ++t) {
        const int cur = t & 1;
        // need B(t) landed; B(t+1) (4 loads) stays in flight except at the last phase
        if (t + 1 < T) {
            asm volatile("s_waitcnt vmcnt(4) lgkmcnt(0)" ::: "memory");
        } else {
            asm volatile("s_waitcnt vmcnt(0) lgkmcnt(0)" ::: "memory");
        }
        __builtin_amdgcn_sched_barrier(0);
        __builtin_amdgcn_s_barrier();          // buffers for phase t fully staged
        __builtin_amdgcn_sched_barrier(0);

        // fragment reads (must complete before barrier2: staging overwrites As/Bs[cur])
        short8 af[2][4], bfr[2][4];
#pragma unroll
        for (int kk = 0; kk < 2; ++kk) {
            const int swz = ((kk * 4 + quad) ^ (lr & 7)) * 8;
#pragma unroll
            for (int i = 0; i < 4; ++i)
                af[kk][i] = *(const short8*)&As[(size_t)(wm0 + i * 16 + lr) * 64 + swz];
#pragma unroll
            for (int j = 0; j < 4; ++j)
                bfr[kk][j] = *(const short8*)&Bs[cur][(size_t)(wn0 + j * 16 + lr) * 64 + swz];
        }
        asm volatile("s_waitcnt lgkmcnt(0)" ::: "memory");
        __builtin_amdgcn_sched_barrier(0);
        __builtin_amdgcn_s_barrier();          // all waves done reading
        __builtin_amdgcn_sched_barrier(0);

        // stage ahead: B(t+2) DMA (flies across next phase), A(t+1) via VALU
        if (t + 2 < T) dmaB(s0 + ((t + 2) >> 1), (t + 2) & 1, Bs[cur]);
        if (t + 1 < T) genA(s0 + ((t + 1) >> 1), (t + 1) & 1);

        __builtin_amdgcn_s_setprio(1);
#pragma unroll
        for (int kk = 0; kk < 2; ++kk)
#pragma unroll
            for (int i = 0; i < 4; ++i)
#pragma unroll
                for (int j = 0; j < 4; ++j)
                    acc[i][j] = __builtin_amdgcn_mfma_f32_16x16x32_bf16(af[kk][i], bfr[kk][j], acc[i][j], 0, 0, 0);
        __builtin_amdgcn_s_setprio(0);
    }

    // ---- epilogue: virtual slices s in [S, s1v), non-pipelined (rare: 1 of ksplit combos) ----
    for (int s = sE; s < s1v; ++s) {
#pragma unroll
        for (int p = 0; p < 2; ++p) {
            __syncthreads();   // full drain; previous phase's reads complete
            dmaB(s, p, Bs[0]);
            if (s == S) {
#pragma unroll
                for (int k2 = 0; k2 < 4; ++k2) {
                    const float* src = h + (size_t)(b0 + tb + 32 * k2) * 1280
                                         + (size_t)(iw + 1) * E_ + p * 64 + teg * 8;
                    float4 v0 = *(const float4*)(src);
                    float4 v1 = *(const float4*)(src + 4);
                    union { ushort o[8]; uint4 v; } u;
                    u.o[0] = f2b(v0.x); u.o[1] = f2b(v0.y); u.o[2] = f2b(v0.z); u.o[3] = f2b(v0.w);
                    u.o[4] = f2b(v1.x); u.o[5] = f2b(v1.y); u.o[6] = f2b(v1.z); u.o[7] = f2b(v1.w);
                    *(uint4*)&As[(size_t)(tb + 32 * k2) * 64 + aswz] = u.v;
                }
            } else {
                int j0 = (s - S - 1) * 128 + p * 64 + teg * 8;
#pragma unroll
                for (int k2 = 0; k2 < 4; ++k2) {
                    int b = b0 + tb + 32 * k2;
                    union { ushort o[8]; uint4 v; } u;
#pragma unroll
                    for (int jjj = 0; jjj < 8; ++jjj) {
                        int sp = j0 + jjj;
                        u.o[jjj] = (sp < S) ? f2b(xT[(size_t)sp * NSAMP + b]) : (ushort)0;
                    }
                    *(uint4*)&As[(size_t)(tb + 32 * k2) * 64 + aswz] = u.v;
                }
            }
            __syncthreads();   // staging (incl. DMA via vmcnt drain) visible
#pragma unroll
            for (int kk = 0; kk < 2; ++kk) {
                const int swz = ((kk * 4 + quad) ^ (lr & 7)) * 8;
                short8 af2[4], bf2[4];
#pragma unroll
                for (int i = 0; i < 4; ++i)
                    af2[i] = *(const short8*)&As[(size_t)(wm0 + i * 16 + lr) * 64 + swz];
#pragma unroll
                for (int j = 0; j < 4; ++j)
                    bf2[j] = *(const short8*)&Bs[0][(size_t)(wn0 + j * 16 + lr) * 64 + swz];
#pragma unroll
                for (int i = 0; i < 4; ++i)
#pragma unroll
                    for (int j = 0; j < 4; ++j)
                        acc[i][j] = __builtin_amdgcn_mfma_f32_16x16x32_bf16(af2[i], bf2[j], acc[i][j], 0, 0, 0);
            }
        }
    }

    // epilogue: C/D layout col=lane&15, row=quad*4+r
    float* dst = partial + (size_t)ks * NSAMP * 256;
#pragma unroll
    for (int i = 0; i < 4; ++i)
#pragma unroll
        for (int j = 0; j < 4; ++j)
#pragma unroll
            for (int r = 0; r < 4; ++r) {
                int row = wm0 + i * 16 + quad * 4 + r;
                int col = wn0 + j * 16 + lr;
                dst[(size_t)(b0 + row) * 256 + m0 + col] = acc[i][j][r];
            }
}

// ==================== small-layer GEMM (M=16) — previous structure ====================
template<int BM, int BN, int WROWS, int WCOLS>
__global__ __launch_bounds__(256, 2) void gemm_k(
    const ushort* __restrict__ wWb, const float* __restrict__ h,
    const float* __restrict__ xT, float* __restrict__ partial,
    int S, int M, int iw, int ksplit, int btiles, int ntiles)
{
    constexpr int SM = BM / WROWS / 16;
    constexpr int SN = BN / WCOLS / 16;
    constexpr int ASLOTS = BM * 8 / 256;
    constexpr int LDA = 72;

    __shared__ ushort As[BM][LDA];
    __shared__ ushort Bs[BN][LDA];

    const int tid = threadIdx.x;
    const int bt = blockIdx.x % btiles;
    const int nt = (blockIdx.x / btiles) % ntiles;
    const int ks = blockIdx.x / (btiles * ntiles);
    const int b0 = bt * BM;
    const int m0 = nt * BN;
    const int total_s = S + 3;
    const int base = total_s / ksplit;
    const int rem = total_s - base * ksplit;
    const int s0 = ks * base + min(ks, rem);
    const int s1 = s0 + base + (ks < rem ? 1 : 0);

    const int lane = tid & 63;
    const int wave = tid >> 6;
    const int quad = lane >> 4;
    const int lr = lane & 15;
    const int wm0 = (wave / WCOLS) * (BM / WROWS);
    const int wn0 = (wave % WCOLS) * (BN / WCOLS);

    const int tb = tid >> 3;
    const int teg = tid & 7;

    float hreg[ASLOTS][2][8];
#pragma unroll
    for (int k2 = 0; k2 < ASLOTS; ++k2) {
        int b = tb + 32 * k2;
#pragma unroll
        for (int p = 0; p < 2; ++p) {
            const float* src = h + (size_t)(b0 + b) * 1280 + (size_t)iw * E_ + p * 64 + teg * 8;
            float4 v0 = *(const float4*)(src);
            float4 v1 = *(const float4*)(src + 4);
            hreg[k2][p][0] = v0.x; hreg[k2][p][1] = v0.y; hreg[k2][p][2] = v0.z; hreg[k2][p][3] = v0.w;
            hreg[k2][p][4] = v1.x; hreg[k2][p][5] = v1.y; hreg[k2][p][6] = v1.z; hreg[k2][p][7] = v1.w;
        }
    }

    floatx4 acc[SM][SN];
#pragma unroll
    for (int i = 0; i < SM; ++i)
#pragma unroll
        for (int j = 0; j < SN; ++j)
            acc[i][j] = (floatx4){0.f, 0.f, 0.f, 0.f};

    for (int s = s0; s < s1; ++s) {
        float xv[ASLOTS];
        if (s < S) {
#pragma unroll
            for (int k2 = 0; k2 < ASLOTS; ++k2)
                xv[k2] = xT[(size_t)s * NSAMP + b0 + tb + 32 * k2];
        }

#pragma unroll
        for (int p = 0; p < 2; ++p) {
            if (s < S) {
#pragma unroll
                for (int k2 = 0; k2 < ASLOTS; ++k2) {
                    union { ushort o[8]; uint4 v; } u;
#pragma unroll
                    for (int j = 0; j < 8; ++j) u.o[j] = f2b(xv[k2] * hreg[k2][p][j]);
                    *(uint4*)&As[tb + 32 * k2][teg * 8] = u.v;
                }
            } else if (s == S) {
#pragma unroll
                for (int k2 = 0; k2 < ASLOTS; ++k2) {
                    const float* src = h + (size_t)(b0 + tb + 32 * k2) * 1280
                                         + (size_t)(iw + 1) * E_ + p * 64 + teg * 8;
                    float4 v0 = *(const float4*)(src);
                    float4 v1 = *(const float4*)(src + 4);
                    union { ushort o[8]; uint4 v; } u;
                    u.o[0] = f2b(v0.x); u.o[1] = f2b(v0.y); u.o[2] = f2b(v0.z); u.o[3] = f2b(v0.w);
                    u.o[4] = f2b(v1.x); u.o[5] = f2b(v1.y); u.o[6] = f2b(v1.z); u.o[7] = f2b(v1.w);
                    *(uint4*)&As[tb + 32 * k2][teg * 8] = u.v;
                }
            } else {
                int j0 = (s - S - 1) * 128 + p * 64 + teg * 8;
#pragma unroll
                for (int k2 = 0; k2 < ASLOTS; ++k2) {
                    int b = b0 + tb + 32 * k2;
                    union { ushort o[8]; uint4 v; } u;
#pragma unroll
                    for (int jj = 0; jj < 8; ++jj) {
                        int sp = j0 + jj;
                        u.o[jj] = (sp < S) ? f2b(xT[(size_t)sp * NSAMP + b]) : (ushort)0;
                    }
                    *(uint4*)&As[tb + 32 * k2][teg * 8] = u.v;
                }
            }
#pragma unroll
            for (int slot = tid; slot < BN * 8; slot += 256) {
                int m = slot >> 3, eg2 = slot & 7;
                *(uint4*)&Bs[m][eg2 * 8] =
                    *(const uint4*)(wWb + ((size_t)s * M + m0 + m) * E_ + p * 64 + eg2 * 8);
            }
            __syncthreads();
#pragma unroll
            for (int kk = 0; kk < 2; ++kk) {
                short8 af[SM], bfr[SN];
#pragma unroll
                for (int i = 0; i < SM; ++i)
                    af[i] = *(const short8*)&As[wm0 + i * 16 + lr][kk * 32 + quad * 8];
#pragma unroll
                for (int j = 0; j < SN; ++j)
                    bfr[j] = *(const short8*)&Bs[wn0 + j * 16 + lr][kk * 32 + quad * 8];
#pragma unroll
                for (int i = 0; i < SM; ++i)
#pragma unroll
                    for (int j = 0; j < SN; ++j)
                        acc[i][j] = __builtin_amdgcn_mfma_f32_16x16x32_bf16(af[i], bfr[j], acc[i][j], 0, 0, 0);
            }
            __syncthreads();
        }
    }

    float* dst = partial + (size_t)ks * NSAMP * M;
#pragma unroll
    for (int i = 0; i < SM; ++i)
#pragma unroll
        for (int j = 0; j < SN; ++j)
#pragma unroll
            for (int r = 0; r < 4; ++r) {
                int row = wm0 + i * 16 + quad * 4 + r;
                int col = wn0 + j * 16 + lr;
                dst[(size_t)(b0 + row) * M + m0 + col] = acc[i][j][r];
            }
}

// -------------------- reduce partials + bb (+ReLU), emit xT fp32 for next layer --------------
__global__ void reduce_mid(const float* __restrict__ partial, const float* __restrict__ bb,
                           float* __restrict__ xTn, int KS, int relu)
{
    __shared__ float t[32][33];
    const int b0 = (blockIdx.x >> 3) * 32;
    const int m0 = (blockIdx.x & 7) * 32;
    const int mo = threadIdx.x & 31;
    const int bs0 = threadIdx.x >> 5;   // 0..7
    const float bv = bb[m0 + mo];
#pragma unroll
    for (int r = 0; r < 4; ++r) {
        const int bs = bs0 + 8 * r;
        const size_t off = (size_t)(b0 + bs) * 256 + m0 + mo;
        float a0 = 0.f, a1 = 0.f, a2 = 0.f, a3 = 0.f;
#pragma unroll
        for (int k = 0; k < 16; k += 4) {
            a0 += partial[(size_t)(k + 0) * (NSAMP * 256) + off];
            a1 += partial[(size_t)(k + 1) * (NSAMP * 256) + off];
            a2 += partial[(size_t)(k + 2) * (NSAMP * 256) + off];
            a3 += partial[(size_t)(k + 3) * (NSAMP * 256) + off];
        }
        float a = (a0 + a1) + (a2 + a3) + bv;
        if (relu) a = fmaxf(a, 0.f);
        t[bs][mo] = a;
    }
    __syncthreads();
    const int bo = threadIdx.x & 31;
    const int ms0 = threadIdx.x >> 5;
#pragma unroll
    for (int r = 0; r < 4; ++r) {
        const int ms = ms0 + 8 * r;
        xTn[(size_t)(m0 + ms) * NSAMP + b0 + bo] = t[bo][ms];
    }
}

// -------------------- final layer reduce -> d_out (fp32, ReLU) --------------------
__global__ void reduce_out(const float* __restrict__ partial, const float* __restrict__ bb,
                           float* __restrict__ out, int KS)
{
    int idx = blockIdx.x * 256 + threadIdx.x;   // < 2048*16
    float a0 = 0.f, a1 = 0.f, a2 = 0.f, a3 = 0.f;
#pragma unroll
    for (int k = 0; k < 64; k += 4) {
        a0 += partial[(size_t)(k + 0) * (NSAMP * 16) + idx];
        a1 += partial[(size_t)(k + 1) * (NSAMP * 16) + idx];
        a2 += partial[(size_t)(k + 2) * (NSAMP * 16) + idx];
        a3 += partial[(size_t)(k + 3) * (NSAMP * 16) + idx];
    }
    out[idx] = fmaxf((a0 + a1) + (a2 + a3) + bb[idx & 15], 0.f);
}

extern "C" void kernel_launch(void* const* d_in, const int* in_sizes, int n_in,
                              void* d_out, int out_size, void* d_ws, size_t ws_size,
                              hipStream_t stream)
{
    const float* input = (const float*)d_in[0];
    const float* l1W   = (const float*)d_in[1];
    const float* l1b   = (const float*)d_in[2];

    char* ws = (char*)d_ws;
    // layout (bytes): wWb 16.98M | h 10.49M | xT0 2M | xT1 2M | partial 33.55M = 65.2MB
    ushort* wWb = (ushort*)(ws + 0);
    float* h    = (float*)(ws + 16975872);
    float* xT0  = (float*)(ws + 27461632);
    float* xT1  = (float*)(ws + 29558784);
    float* part = (float*)(ws + 31655936);

    hipLaunchKernelGGL(hyper_h, dim3(2048 * 5), dim3(256), 0, stream, input, l1W, l1b, h);
    hipLaunchKernelGGL(x0_t, dim3(176 * 2048 / 256), dim3(256), 0, stream, input, xT0);

    const int S_[5] = {176, 256, 256, 256, 256};
    const int M_[5] = {256, 256, 256, 256, 16};
    float* xt[2] = {xT0, xT1};

    for (int i = 0; i < 5; ++i) {
        const float* wW = (const float*)d_in[3 + 4 * i];
        const float* wb = (const float*)d_in[4 + 4 * i];
        const float* bW = (const float*)d_in[5 + 4 * i];
        const float* bb = (const float*)d_in[6 + 4 * i];
        float* xin = xt[i & 1];
        int n = S_[i] * M_[i] * E_;
        hipLaunchKernelGGL(cvt_bf16, dim3(n / 2048), dim3(256), 0, stream, wW, wWb, n);
        hipLaunchKernelGGL(cvt_bias, dim3(3 * M_[i] * E_ / 256), dim3(256), 0, stream,
                           bW, wb, wWb, S_[i], M_[i]);

        if (M_[i] == 256) {
            const int btiles = 16, ntiles = 2, ksplit = 16;
            hipLaunchKernelGGL(gemm_big, dim3(btiles * ntiles * ksplit), dim3(256), 0, stream,
                               wWb, h, xin, part, S_[i], 2 * i, ksplit, btiles, ntiles);
            hipLaunchKernelGGL(reduce_mid, dim3(512), dim3(256), 0, stream,
                               part, bb, xt[(i + 1) & 1], ksplit, (i < 3) ? 1 : 0);
        } else {
            const int btiles = 8, ntiles = 1, ksplit = 64;
            hipLaunchKernelGGL((gemm_k<256, 16, 4, 1>), dim3(btiles * ntiles * ksplit), dim3(256), 0, stream,
                               wWb, h, xin, part, S_[i], 16, 2 * i, ksplit, btiles, ntiles);
            hipLaunchKernelGGL(reduce_out, dim3(128), dim3(256), 0, stream,
                               part, bb, (float*)d_out, ksplit);
        }
    }
}

// Round 3
// 527.507 us; speedup vs baseline: 1.3741x; 1.3521x over previous
//
#include <hip/hip_runtime.h>
#include <hip/hip_bf16.h>

#define E_ 128
#define NSAMP 2048

typedef __attribute__((ext_vector_type(8))) short short8;
typedef __attribute__((ext_vector_type(4))) float floatx4;

__device__ __forceinline__ ushort f2b(float f) {
    union { __hip_bfloat16 h; ushort u; } cv;
    cv.h = __float2bfloat16(f);
    return cv.u;
}

__device__ __forceinline__ void gload_lds16(const ushort* g, ushort* l) {
    __builtin_amdgcn_global_load_lds(
        (const __attribute__((address_space(1))) void*)g,
        (__attribute__((address_space(3))) void*)l, 16, 0, 0);
}

// -------------------- h = ReLU(ids @ l1W^T + l1b), fp32 --------------------
__global__ void hyper_h(const float* __restrict__ input, const float* __restrict__ l1W,
                        const float* __restrict__ l1b, float* __restrict__ h)
{
    int b = blockIdx.x / 5;
    int o = (blockIdx.x % 5) * 256 + threadIdx.x;
    const float* ids = input + (size_t)b * 192 + 176;
    const float* w = l1W + (size_t)o * 16;
    float a = l1b[o];
#pragma unroll
    for (int i = 0; i < 16; i += 4) {
        float4 wv = *(const float4*)(w + i);
        a += ids[i] * wv.x + ids[i + 1] * wv.y + ids[i + 2] * wv.z + ids[i + 3] * wv.w;
    }
    h[(size_t)b * 1280 + o] = fmaxf(a, 0.f);
}

// -------------------- xT0[s][b] = input[b][s]  (s < 176), fp32 --------------------
__global__ void x0_t(const float* __restrict__ input, float* __restrict__ xT0)
{
    int idx = blockIdx.x * 256 + threadIdx.x;   // < 176*2048
    int s = idx >> 11, b = idx & 2047;
    xT0[idx] = input[(size_t)b * 192 + s];
}

// -------------------- fp32 -> bf16 convert (wW bulk) --------------------
__global__ void cvt_bf16(const float* __restrict__ src, ushort* __restrict__ dst, int n)
{
    int i = (blockIdx.x * 256 + threadIdx.x) * 8;
    if (i >= n) return;
    float4 a = *(const float4*)(src + i);
    float4 b = *(const float4*)(src + i + 4);
    union { ushort o[8]; uint4 v; } u;
    u.o[0] = f2b(a.x); u.o[1] = f2b(a.y); u.o[2] = f2b(a.z); u.o[3] = f2b(a.w);
    u.o[4] = f2b(b.x); u.o[5] = f2b(b.y); u.o[6] = f2b(b.z); u.o[7] = f2b(b.w);
    *(uint4*)(dst + i) = u.v;
}

// -------------------- build 3 virtual B-slices: [S]=bW rows, [S+1..S+2]=wb^T chunks --------
__global__ void cvt_bias(const float* __restrict__ bW, const float* __restrict__ wb,
                         ushort* __restrict__ dst, int S, int M)
{
    int idx = blockIdx.x * 256 + threadIdx.x;   // < 3*M*E_
    int slice = idx / (M * E_);
    int rem = idx - slice * (M * E_);
    int m = rem / E_, e = rem - m * E_;
    ushort v;
    if (slice == 0) {
        v = f2b(bW[(size_t)m * E_ + e]);
    } else {
        int s = (slice - 1) * 128 + e;
        v = (s < S) ? f2b(wb[(size_t)s * M + m]) : (ushort)0;
    }
    dst[(size_t)(S + slice) * M * E_ + rem] = v;
}

// ==================== big-layer GEMM (M=256): register-A, single-barrier pipeline ====================
// BM=128, BN=128, 4 waves, each wave owns 32 rows x all 128 cols.
// A = x[b,s]*h[b,e] generated IN REGISTERS (h fp32 in 64 VGPR/lane, quad-sliced) ->
// no A LDS round-trip, one barrier per phase.
// B: Bs ring of 4 buffers (16KB each), global_load_lds DMA issued 3 phases ahead,
// steady-state s_waitcnt vmcnt(8) (never drains mid-loop). XOR-swizzled 16B groups.
// Virtual slices (s >= S) peeled to a non-pipelined __syncthreads epilogue.
__global__ __launch_bounds__(256, 2) void gemm_big(
    const ushort* __restrict__ wWb, const float* __restrict__ h,
    const float* __restrict__ xT, float* __restrict__ partial,
    int S, int iw, int ksplit, int btiles, int ntiles)
{
    __shared__ __align__(16) ushort Bs[4 * 128 * 64];
    __shared__ __align__(16) float xs[17 * 128];

    const int tid = threadIdx.x;
    // XCD-aware decode: combo (nt,ks) pinned to one XCD, its 16 bt-blocks contiguous there.
    const int bid = blockIdx.x;
    const int xcd = bid & 7;
    const int jj_ = bid >> 3;
    const int combo = xcd + 8 * (jj_ / btiles);
    const int bt = jj_ % btiles;
    const int nt = combo % ntiles;
    const int ks = combo / ntiles;
    const int b0 = bt * 128;
    const int m0 = nt * 128;
    const int total_s = S + 3;
    const int base = total_s / ksplit;
    const int rem = total_s - base * ksplit;
    const int s0 = ks * base + min(ks, rem);
    const int s1v = s0 + base + (ks < rem ? 1 : 0);
    const int sE = min(s1v, S);     // main loop covers [s0, sE)
    const int ns = sE - s0;
    const int T = 2 * ns;           // phases

    const int lane = tid & 63;
    const int wave = tid >> 6;
    const int quad = lane >> 4;
    const int lr = lane & 15;
    const int wm0 = wave * 32;      // wave rows: 32; wave cols: all 128

    const int brow = lane >> 3;         // B-DMA local row (0..7)
    const int bgg = (lane & 7) ^ brow;  // global e-group for this lane's slot

    // h fragments in registers: hreg[i][p][kk][j] = h[b0+wm0+i*16+lr][iw*128 + p*64 + kk*32 + quad*8 + j]
    float hreg[2][2][2][8];
#pragma unroll
    for (int i = 0; i < 2; ++i)
#pragma unroll
        for (int p = 0; p < 2; ++p)
#pragma unroll
            for (int kk = 0; kk < 2; ++kk) {
                const float* src = h + (size_t)(b0 + wm0 + i * 16 + lr) * 1280
                                     + (size_t)iw * E_ + p * 64 + kk * 32 + quad * 8;
                float4 v0 = *(const float4*)(src);
                float4 v1 = *(const float4*)(src + 4);
                hreg[i][p][kk][0] = v0.x; hreg[i][p][kk][1] = v0.y;
                hreg[i][p][kk][2] = v0.z; hreg[i][p][kk][3] = v0.w;
                hreg[i][p][kk][4] = v1.x; hreg[i][p][kk][5] = v1.y;
                hreg[i][p][kk][6] = v1.z; hreg[i][p][kk][7] = v1.w;
            }

    // stage x-slice: xs[si][b_local]
    for (int idx = tid; idx < ns * 128; idx += 256) {
        int j = idx >> 7, bb2 = idx & 127;
        xs[idx] = xT[(size_t)(s0 + j) * NSAMP + b0 + bb2];
    }

    floatx4 acc[2][8];
#pragma unroll
    for (int i = 0; i < 2; ++i)
#pragma unroll
        for (int j = 0; j < 8; ++j)
            acc[i][j] = (floatx4){0.f, 0.f, 0.f, 0.f};

    auto dmaB = [&](int s, int p, ushort* buf) {
#pragma unroll
        for (int t4 = 0; t4 < 4; ++t4) {
            int rloc = wave * 32 + t4 * 8;
            const ushort* gp = wWb + ((size_t)s * 256 + m0 + rloc + brow) * E_ + p * 64 + bgg * 8;
            gload_lds16(gp, buf + (size_t)rloc * 64 + lane * 8);
        }
    };

    // prologue: drain everything (hreg/xs loads), then put 3 phases of B DMA in flight
    __builtin_amdgcn_sched_barrier(0);
    __syncthreads();
    __builtin_amdgcn_sched_barrier(0);
#pragma unroll
    for (int pt = 0; pt < 3; ++pt)
        if (pt < T) dmaB(s0 + (pt >> 1), pt & 1, Bs + (size_t)(pt & 3) * (128 * 64));

    for (int si = 0; si < ns; ++si) {
        float xr0 = 0.f, xr1 = 0.f;
#pragma unroll
        for (int P = 0; P < 2; ++P) {
            const int t2 = 2 * si + P;
            const int left = T - 1 - t2;
            if (left >= 2)      asm volatile("s_waitcnt vmcnt(8)" ::: "memory");
            else if (left == 1) asm volatile("s_waitcnt vmcnt(4)" ::: "memory");
            else                asm volatile("s_waitcnt vmcnt(0)" ::: "memory");
            __builtin_amdgcn_sched_barrier(0);
            __builtin_amdgcn_s_barrier();
            __builtin_amdgcn_sched_barrier(0);

            if (t2 + 3 < T) {
                const int tn = t2 + 3;
                dmaB(s0 + (tn >> 1), tn & 1, Bs + (size_t)(tn & 3) * (128 * 64));
            }
            if (P == 0) {
                xr0 = xs[si * 128 + wm0 + lr];
                xr1 = xs[si * 128 + wm0 + 16 + lr];
            }
            const ushort* bcur = Bs + (size_t)(t2 & 3) * (128 * 64);
#pragma unroll
            for (int kk = 0; kk < 2; ++kk) {
                short8 bfr[8];
#pragma unroll
                for (int j = 0; j < 8; ++j) {
                    const int row = j * 16 + lr;
                    const int swz = ((kk * 4 + quad) ^ (lr & 7)) * 8;
                    bfr[j] = *(const short8*)&bcur[(size_t)row * 64 + swz];
                }
                short8 af0, af1;
#pragma unroll
                for (int jj = 0; jj < 8; ++jj) {
                    af0[jj] = (short)f2b(xr0 * hreg[0][P][kk][jj]);
                    af1[jj] = (short)f2b(xr1 * hreg[1][P][kk][jj]);
                }
#pragma unroll
                for (int j = 0; j < 8; ++j) {
                    acc[0][j] = __builtin_amdgcn_mfma_f32_16x16x32_bf16(af0, bfr[j], acc[0][j], 0, 0, 0);
                    acc[1][j] = __builtin_amdgcn_mfma_f32_16x16x32_bf16(af1, bfr[j], acc[1][j], 0, 0, 0);
                }
            }
        }
    }

    // ---- virtual slices s in [S, s1v): non-pipelined (only last-ks blocks) ----
    for (int s = sE; s < s1v; ++s) {
        for (int p = 0; p < 2; ++p) {
            __syncthreads();            // previous phase's reads complete (full drain)
            dmaB(s, p, Bs);
            short8 af[2][2];            // [kk][i]
            if (s == S) {
#pragma unroll
                for (int kk = 0; kk < 2; ++kk)
#pragma unroll
                    for (int i = 0; i < 2; ++i) {
                        const float* src = h + (size_t)(b0 + wm0 + i * 16 + lr) * 1280
                                             + (size_t)(iw + 1) * E_ + p * 64 + kk * 32 + quad * 8;
                        float4 v0 = *(const float4*)(src);
                        float4 v1 = *(const float4*)(src + 4);
                        af[kk][i][0] = (short)f2b(v0.x); af[kk][i][1] = (short)f2b(v0.y);
                        af[kk][i][2] = (short)f2b(v0.z); af[kk][i][3] = (short)f2b(v0.w);
                        af[kk][i][4] = (short)f2b(v1.x); af[kk][i][5] = (short)f2b(v1.y);
                        af[kk][i][6] = (short)f2b(v1.z); af[kk][i][7] = (short)f2b(v1.w);
                    }
            } else {
                const int jbase = (s - S - 1) * 128 + p * 64;
#pragma unroll
                for (int kk = 0; kk < 2; ++kk)
#pragma unroll
                    for (int i = 0; i < 2; ++i) {
                        const int b = b0 + wm0 + i * 16 + lr;
#pragma unroll
                        for (int jj = 0; jj < 8; ++jj) {
                            const int sp = jbase + kk * 32 + quad * 8 + jj;
                            af[kk][i][jj] = (sp < S) ? (short)f2b(xT[(size_t)sp * NSAMP + b]) : (short)0;
                        }
                    }
            }
            __syncthreads();            // DMA + af loads drained (compiler waits)
#pragma unroll
            for (int kk = 0; kk < 2; ++kk) {
                short8 bfr[8];
#pragma unroll
                for (int j = 0; j < 8; ++j) {
                    const int row = j * 16 + lr;
                    const int swz = ((kk * 4 + quad) ^ (lr & 7)) * 8;
                    bfr[j] = *(const short8*)&Bs[(size_t)row * 64 + swz];
                }
#pragma unroll
                for (int j = 0; j < 8; ++j) {
                    acc[0][j] = __builtin_amdgcn_mfma_f32_16x16x32_bf16(af[kk][0], bfr[j], acc[0][j], 0, 0, 0);
                    acc[1][j] = __builtin_amdgcn_mfma_f32_16x16x32_bf16(af[kk][1], bfr[j], acc[1][j], 0, 0, 0);
                }
            }
        }
    }

    // C-write: C/D layout col=lane&15, row=quad*4+r
    float* dst = partial + (size_t)ks * NSAMP * 256;
#pragma unroll
    for (int i = 0; i < 2; ++i)
#pragma unroll
        for (int j = 0; j < 8; ++j)
#pragma unroll
            for (int r = 0; r < 4; ++r) {
                const int row = wm0 + i * 16 + quad * 4 + r;
                const int col = j * 16 + lr;
                dst[(size_t)(b0 + row) * 256 + m0 + col] = acc[i][j][r];
            }
}

// ==================== small-layer GEMM (M=16) — previous structure ====================
template<int BM, int BN, int WROWS, int WCOLS>
__global__ __launch_bounds__(256, 2) void gemm_k(
    const ushort* __restrict__ wWb, const float* __restrict__ h,
    const float* __restrict__ xT, float* __restrict__ partial,
    int S, int M, int iw, int ksplit, int btiles, int ntiles)
{
    constexpr int SM = BM / WROWS / 16;
    constexpr int SN = BN / WCOLS / 16;
    constexpr int ASLOTS = BM * 8 / 256;
    constexpr int LDA = 72;

    __shared__ ushort As[BM][LDA];
    __shared__ ushort Bs[BN][LDA];

    const int tid = threadIdx.x;
    const int bt = blockIdx.x % btiles;
    const int nt = (blockIdx.x / btiles) % ntiles;
    const int ks = blockIdx.x / (btiles * ntiles);
    const int b0 = bt * BM;
    const int m0 = nt * BN;
    const int total_s = S + 3;
    const int base = total_s / ksplit;
    const int rem = total_s - base * ksplit;
    const int s0 = ks * base + min(ks, rem);
    const int s1 = s0 + base + (ks < rem ? 1 : 0);

    const int lane = tid & 63;
    const int wave = tid >> 6;
    const int quad = lane >> 4;
    const int lr = lane & 15;
    const int wm0 = (wave / WCOLS) * (BM / WROWS);
    const int wn0 = (wave % WCOLS) * (BN / WCOLS);

    const int tb = tid >> 3;
    const int teg = tid & 7;

    float hreg[ASLOTS][2][8];
#pragma unroll
    for (int k2 = 0; k2 < ASLOTS; ++k2) {
        int b = tb + 32 * k2;
#pragma unroll
        for (int p = 0; p < 2; ++p) {
            const float* src = h + (size_t)(b0 + b) * 1280 + (size_t)iw * E_ + p * 64 + teg * 8;
            float4 v0 = *(const float4*)(src);
            float4 v1 = *(const float4*)(src + 4);
            hreg[k2][p][0] = v0.x; hreg[k2][p][1] = v0.y; hreg[k2][p][2] = v0.z; hreg[k2][p][3] = v0.w;
            hreg[k2][p][4] = v1.x; hreg[k2][p][5] = v1.y; hreg[k2][p][6] = v1.z; hreg[k2][p][7] = v1.w;
        }
    }

    floatx4 acc[SM][SN];
#pragma unroll
    for (int i = 0; i < SM; ++i)
#pragma unroll
        for (int j = 0; j < SN; ++j)
            acc[i][j] = (floatx4){0.f, 0.f, 0.f, 0.f};

    for (int s = s0; s < s1; ++s) {
        float xv[ASLOTS];
        if (s < S) {
#pragma unroll
            for (int k2 = 0; k2 < ASLOTS; ++k2)
                xv[k2] = xT[(size_t)s * NSAMP + b0 + tb + 32 * k2];
        }

#pragma unroll
        for (int p = 0; p < 2; ++p) {
            if (s < S) {
#pragma unroll
                for (int k2 = 0; k2 < ASLOTS; ++k2) {
                    union { ushort o[8]; uint4 v; } u;
#pragma unroll
                    for (int j = 0; j < 8; ++j) u.o[j] = f2b(xv[k2] * hreg[k2][p][j]);
                    *(uint4*)&As[tb + 32 * k2][teg * 8] = u.v;
                }
            } else if (s == S) {
#pragma unroll
                for (int k2 = 0; k2 < ASLOTS; ++k2) {
                    const float* src = h + (size_t)(b0 + tb + 32 * k2) * 1280
                                         + (size_t)(iw + 1) * E_ + p * 64 + teg * 8;
                    float4 v0 = *(const float4*)(src);
                    float4 v1 = *(const float4*)(src + 4);
                    union { ushort o[8]; uint4 v; } u;
                    u.o[0] = f2b(v0.x); u.o[1] = f2b(v0.y); u.o[2] = f2b(v0.z); u.o[3] = f2b(v0.w);
                    u.o[4] = f2b(v1.x); u.o[5] = f2b(v1.y); u.o[6] = f2b(v1.z); u.o[7] = f2b(v1.w);
                    *(uint4*)&As[tb + 32 * k2][teg * 8] = u.v;
                }
            } else {
                int j0 = (s - S - 1) * 128 + p * 64 + teg * 8;
#pragma unroll
                for (int k2 = 0; k2 < ASLOTS; ++k2) {
                    int b = b0 + tb + 32 * k2;
                    union { ushort o[8]; uint4 v; } u;
#pragma unroll
                    for (int jj = 0; jj < 8; ++jj) {
                        int sp = j0 + jj;
                        u.o[jj] = (sp < S) ? f2b(xT[(size_t)sp * NSAMP + b]) : (ushort)0;
                    }
                    *(uint4*)&As[tb + 32 * k2][teg * 8] = u.v;
                }
            }
#pragma unroll
            for (int slot = tid; slot < BN * 8; slot += 256) {
                int m = slot >> 3, eg2 = slot & 7;
                *(uint4*)&Bs[m][eg2 * 8] =
                    *(const uint4*)(wWb + ((size_t)s * M + m0 + m) * E_ + p * 64 + eg2 * 8);
            }
            __syncthreads();
#pragma unroll
            for (int kk = 0; kk < 2; ++kk) {
                short8 af[SM], bfr[SN];
#pragma unroll
                for (int i = 0; i < SM; ++i)
                    af[i] = *(const short8*)&As[wm0 + i * 16 + lr][kk * 32 + quad * 8];
#pragma unroll
                for (int j = 0; j < SN; ++j)
                    bfr[j] = *(const short8*)&Bs[wn0 + j * 16 + lr][kk * 32 + quad * 8];
#pragma unroll
                for (int i = 0; i < SM; ++i)
#pragma unroll
                    for (int j = 0; j < SN; ++j)
                        acc[i][j] = __builtin_amdgcn_mfma_f32_16x16x32_bf16(af[i], bfr[j], acc[i][j], 0, 0, 0);
            }
            __syncthreads();
        }
    }

    float* dst = partial + (size_t)ks * NSAMP * M;
#pragma unroll
    for (int i = 0; i < SM; ++i)
#pragma unroll
        for (int j = 0; j < SN; ++j)
#pragma unroll
            for (int r = 0; r < 4; ++r) {
                int row = wm0 + i * 16 + quad * 4 + r;
                int col = wn0 + j * 16 + lr;
                dst[(size_t)(b0 + row) * M + m0 + col] = acc[i][j][r];
            }
}

// -------------------- reduce partials + bb (+ReLU), emit xT fp32 for next layer --------------
__global__ void reduce_mid(const float* __restrict__ partial, const float* __restrict__ bb,
                           float* __restrict__ xTn, int KS, int relu)
{
    __shared__ float t[32][33];
    const int b0 = (blockIdx.x >> 3) * 32;
    const int m0 = (blockIdx.x & 7) * 32;
    const int mo = threadIdx.x & 31;
    const int bs0 = threadIdx.x >> 5;   // 0..7
    const float bv = bb[m0 + mo];
#pragma unroll
    for (int r = 0; r < 4; ++r) {
        const int bs = bs0 + 8 * r;
        const size_t off = (size_t)(b0 + bs) * 256 + m0 + mo;
        float a0 = 0.f, a1 = 0.f, a2 = 0.f, a3 = 0.f;
#pragma unroll
        for (int k = 0; k < 16; k += 4) {
            a0 += partial[(size_t)(k + 0) * (NSAMP * 256) + off];
            a1 += partial[(size_t)(k + 1) * (NSAMP * 256) + off];
            a2 += partial[(size_t)(k + 2) * (NSAMP * 256) + off];
            a3 += partial[(size_t)(k + 3) * (NSAMP * 256) + off];
        }
        float a = (a0 + a1) + (a2 + a3) + bv;
        if (relu) a = fmaxf(a, 0.f);
        t[bs][mo] = a;
    }
    __syncthreads();
    const int bo = threadIdx.x & 31;
    const int ms0 = threadIdx.x >> 5;
#pragma unroll
    for (int r = 0; r < 4; ++r) {
        const int ms = ms0 + 8 * r;
        xTn[(size_t)(m0 + ms) * NSAMP + b0 + bo] = t[bo][ms];
    }
}

// -------------------- final layer reduce -> d_out (fp32, ReLU) --------------------
__global__ void reduce_out(const float* __restrict__ partial, const float* __restrict__ bb,
                           float* __restrict__ out, int KS)
{
    int idx = blockIdx.x * 256 + threadIdx.x;   // < 2048*16
    float a0 = 0.f, a1 = 0.f, a2 = 0.f, a3 = 0.f;
#pragma unroll
    for (int k = 0; k < 64; k += 4) {
        a0 += partial[(size_t)(k + 0) * (NSAMP * 16) + idx];
        a1 += partial[(size_t)(k + 1) * (NSAMP * 16) + idx];
        a2 += partial[(size_t)(k + 2) * (NSAMP * 16) + idx];
        a3 += partial[(size_t)(k + 3) * (NSAMP * 16) + idx];
    }
    out[idx] = fmaxf((a0 + a1) + (a2 + a3) + bb[idx & 15], 0.f);
}

extern "C" void kernel_launch(void* const* d_in, const int* in_sizes, int n_in,
                              void* d_out, int out_size, void* d_ws, size_t ws_size,
                              hipStream_t stream)
{
    const float* input = (const float*)d_in[0];
    const float* l1W   = (const float*)d_in[1];
    const float* l1b   = (const float*)d_in[2];

    char* ws = (char*)d_ws;
    // layout (bytes): wWb 16.98M | h 10.49M | xT0 2M | xT1 2M | partial 33.55M = 65.2MB
    ushort* wWb = (ushort*)(ws + 0);
    float* h    = (float*)(ws + 16975872);
    float* xT0  = (float*)(ws + 27461632);
    float* xT1  = (float*)(ws + 29558784);
    float* part = (float*)(ws + 31655936);

    hipLaunchKernelGGL(hyper_h, dim3(2048 * 5), dim3(256), 0, stream, input, l1W, l1b, h);
    hipLaunchKernelGGL(x0_t, dim3(176 * 2048 / 256), dim3(256), 0, stream, input, xT0);

    const int S_[5] = {176, 256, 256, 256, 256};
    const int M_[5] = {256, 256, 256, 256, 16};
    float* xt[2] = {xT0, xT1};

    for (int i = 0; i < 5; ++i) {
        const float* wW = (const float*)d_in[3 + 4 * i];
        const float* wb = (const float*)d_in[4 + 4 * i];
        const float* bW = (const float*)d_in[5 + 4 * i];
        const float* bb = (const float*)d_in[6 + 4 * i];
        float* xin = xt[i & 1];
        int n = S_[i] * M_[i] * E_;
        hipLaunchKernelGGL(cvt_bf16, dim3(n / 2048), dim3(256), 0, stream, wW, wWb, n);
        hipLaunchKernelGGL(cvt_bias, dim3(3 * M_[i] * E_ / 256), dim3(256), 0, stream,
                           bW, wb, wWb, S_[i], M_[i]);

        if (M_[i] == 256) {
            const int btiles = 16, ntiles = 2, ksplit = 16;
            hipLaunchKernelGGL(gemm_big, dim3(btiles * ntiles * ksplit), dim3(256), 0, stream,
                               wWb, h, xin, part, S_[i], 2 * i, ksplit, btiles, ntiles);
            hipLaunchKernelGGL(reduce_mid, dim3(512), dim3(256), 0, stream,
                               part, bb, xt[(i + 1) & 1], ksplit, (i < 3) ? 1 : 0);
        } else {
            const int btiles = 8, ntiles = 1, ksplit = 64;
            hipLaunchKernelGGL((gemm_k<256, 16, 4, 1>), dim3(btiles * ntiles * ksplit), dim3(256), 0, stream,
                               wWb, h, xin, part, S_[i], 16, 2 * i, ksplit, btiles, ntiles);
            hipLaunchKernelGGL(reduce_out, dim3(128), dim3(256), 0, stream,
                               part, bb, (float*)d_out, ksplit);
        }
    }
}